// Round 10
// baseline (779.025 us; speedup 1.0000x reference)
//
#include <hip/hip_runtime.h>
#include <cstdint>
#include <cmath>

typedef __bf16 bf16_t;
typedef __attribute__((ext_vector_type(8))) __bf16 bf16x8;
typedef __attribute__((ext_vector_type(4))) float f32x4;

#define AS_G(x) ((__attribute__((address_space(1))) void*)(x))
#define AS_L(x) ((__attribute__((address_space(3))) void*)(x))

#define BK 64

// problem constants
#define BSZ 8
#define NTOK 1024
#define CC2 512
#define KVD 1792
#define NH 4
#define FFD 2048
#define ROWS 8192  // B*N

// sync/wait primitives: asm with memory clobber so the compiler cannot hoist LDS
// reads above a gate barrier or sink DMA issues below it.
#define BARM()   asm volatile("s_barrier" ::: "memory")
#define VMCNT8() asm volatile("s_waitcnt vmcnt(8)" ::: "memory")
#define VMCNT4() asm volatile("s_waitcnt vmcnt(4)" ::: "memory")
#define VMCNT0() asm volatile("s_waitcnt vmcnt(0)" ::: "memory")
#define LGKMD()  asm volatile("s_waitcnt lgkmcnt(0)" ::: "memory")

// ---------------- 128x128 GEMM core, 256 threads (round-2 proven form) --------------------
// LDS layout: lds[r][slot] holds global[r][slot ^ (r&7)] in 16B chunks (8 bf16).
// Per tile: [stage t+1 -> other buf][vmcnt(8)][barrier][compute (compiler-scheduled)]
//           [lgkmcnt(0)][barrier].

__device__ __forceinline__ void stage_pair(const bf16_t* __restrict__ A,
                                           const bf16_t* __restrict__ B,
                                           int ld, bf16_t* ldsA, bf16_t* ldsB, int tid)
{
#pragma unroll
  for (int it = 0; it < 4; ++it) {
    int chunk = it * 256 + tid;          // 0..1023
    int r = chunk >> 3;                  // 0..127
    int s = chunk & 7;                   // lds slot (16B chunk)
    int cg = ((s ^ (r & 7)) << 3);       // swizzled global column (elements)
    __builtin_amdgcn_global_load_lds(AS_G(A + (long)r * ld + cg),
                                     AS_L(ldsA + chunk * 8), 16, 0, 0);
    __builtin_amdgcn_global_load_lds(AS_G(B + (long)r * ld + cg),
                                     AS_L(ldsB + chunk * 8), 16, 0, 0);
  }
}

__device__ __forceinline__ void mfma_step(const bf16_t* ldsA, const bf16_t* ldsB,
                                          f32x4 acc[4][4], int wr, int wc, int lane, int kc)
{
  const int quad = lane >> 4, l16 = lane & 15;
  bf16x8 a[4], b[4];
#pragma unroll
  for (int i = 0; i < 4; ++i) {
    int r = wr * 64 + i * 16 + l16;
    int slot = (kc + quad) ^ (r & 7);
    a[i] = *(const bf16x8*)(ldsA + r * BK + slot * 8);
  }
#pragma unroll
  for (int j = 0; j < 4; ++j) {
    int r = wc * 64 + j * 16 + l16;
    int slot = (kc + quad) ^ (r & 7);
    b[j] = *(const bf16x8*)(ldsB + r * BK + slot * 8);
  }
#pragma unroll
  for (int i = 0; i < 4; ++i)
#pragma unroll
    for (int j = 0; j < 4; ++j)
      acc[i][j] = __builtin_amdgcn_mfma_f32_16x16x32_bf16(a[i], b[j], acc[i][j], 0, 0, 0);
}

#define GEMM_PROLOG() \
  __shared__ __align__(16) bf16_t ldsA[2][128 * BK]; \
  __shared__ __align__(16) bf16_t ldsB[2][128 * BK]; \
  const int tid = threadIdx.x; \
  const int wave = tid >> 6, lane = tid & 63; \
  const int wr = wave >> 1, wc = wave & 1; \
  f32x4 acc[4][4] = {};

#define GEMM_LOOP(Aptr, Bptr, Kdim) { \
  const bf16_t* Ap_ = (Aptr); const bf16_t* Bp_ = (Bptr); const int Kd_ = (Kdim); \
  const int nt_ = Kd_ / BK; \
  stage_pair(Ap_, Bp_, Kd_, ldsA[0], ldsB[0], tid); \
  for (int t = 0; t < nt_; ++t) { \
    const int cur = t & 1; \
    if (t + 1 < nt_) { \
      stage_pair(Ap_ + (t + 1) * BK, Bp_ + (t + 1) * BK, Kd_, ldsA[cur ^ 1], ldsB[cur ^ 1], tid); \
      VMCNT8(); \
    } else { VMCNT0(); } \
    BARM(); \
    mfma_step(ldsA[cur], ldsB[cur], acc, wr, wc, lane, 0); \
    mfma_step(ldsA[cur], ldsB[cur], acc, wr, wc, lane, 4); \
    LGKMD(); \
    BARM(); \
  } }

template <typename F>
__device__ __forceinline__ void epilogue_apply(f32x4 acc[4][4], int wr, int wc, int lane, F f)
{
  const int quad = lane >> 4, l16 = lane & 15;
#pragma unroll
  for (int i = 0; i < 4; ++i)
#pragma unroll
    for (int j = 0; j < 4; ++j)
#pragma unroll
      for (int r = 0; r < 4; ++r)
        f(wr * 64 + i * 16 + quad * 4 + r, wc * 64 + j * 16 + l16, acc[i][j][r]);
}

// ---------------- 128x128 high-occupancy core, 512 threads ("w-core") ---------------------
// OCCUPANCY lever (rocprof signature: MfmaUtil 23 / VALU 11 / HBM 12 / Occ 17 ->
// latency-bound, "smaller LDS tiles, bigger grid"): 8 waves x 64x32 output each,
// dbuf LDS = 64 KB -> 2 blocks/CU = 16 waves/CU = 4 waves/SIMD (vs 2 for the 256^2 core).
// Barriers sync only half a CU's waves; the co-resident block fills the stall.
// Same proven sync skeleton, 16x16 fragments (0 bank conflicts; 32x32 measured 4.8M),
// same chunk swizzle. Stage = 4 loads/thread -> vmcnt(4) counted gate.

__device__ __forceinline__ void stage_w(const bf16_t* __restrict__ A,
                                        const bf16_t* __restrict__ B,
                                        int ld, bf16_t* ldsA, bf16_t* ldsB, int tid)
{
#pragma unroll
  for (int it = 0; it < 2; ++it) {
    int chunk = it * 512 + tid;          // 0..1023
    int r = chunk >> 3;                  // 0..127
    int s = chunk & 7;
    int cg = ((s ^ (r & 7)) << 3);
    __builtin_amdgcn_global_load_lds(AS_G(A + (long)r * ld + cg),
                                     AS_L(ldsA + chunk * 8), 16, 0, 0);
    __builtin_amdgcn_global_load_lds(AS_G(B + (long)r * ld + cg),
                                     AS_L(ldsB + chunk * 8), 16, 0, 0);
  }
}

__device__ __forceinline__ void mfma_w(const bf16_t* ldsA, const bf16_t* ldsB,
                                       f32x4 acc[4][2], int wr, int wc, int lane)
{
  const int quad = lane >> 4, l16 = lane & 15;
  bf16x8 a[4][2], b[2][2];
#pragma unroll
  for (int i = 0; i < 4; ++i)
#pragma unroll
    for (int kc = 0; kc < 2; ++kc) {
      int r = wr * 64 + i * 16 + l16;
      int slot = (kc * 4 + quad) ^ (r & 7);
      a[i][kc] = *(const bf16x8*)(ldsA + r * BK + slot * 8);
    }
#pragma unroll
  for (int j = 0; j < 2; ++j)
#pragma unroll
    for (int kc = 0; kc < 2; ++kc) {
      int r = wc * 32 + j * 16 + l16;
      int slot = (kc * 4 + quad) ^ (r & 7);
      b[j][kc] = *(const bf16x8*)(ldsB + r * BK + slot * 8);
    }
#pragma unroll
  for (int i = 0; i < 4; ++i)
#pragma unroll
    for (int j = 0; j < 2; ++j)
#pragma unroll
      for (int kc = 0; kc < 2; ++kc)
        acc[i][j] = __builtin_amdgcn_mfma_f32_16x16x32_bf16(a[i][kc], b[j][kc],
                                                            acc[i][j], 0, 0, 0);
}

#define GEMMW_PROLOG() \
  __shared__ __align__(16) bf16_t ldsA[2][128 * BK]; \
  __shared__ __align__(16) bf16_t ldsB[2][128 * BK]; \
  __shared__ float sred[16]; \
  (void)sred; \
  const int tid = threadIdx.x; \
  const int wave = tid >> 6, lane = tid & 63; \
  const int wr = wave >> 2, wc = wave & 3; \
  f32x4 acc[4][2] = {};

#define GEMMW_LOOP(Aptr, Bptr, Kdim) { \
  const bf16_t* Ap_ = (Aptr); const bf16_t* Bp_ = (Bptr); const int Kd_ = (Kdim); \
  const int nt_ = Kd_ / BK; \
  stage_w(Ap_, Bp_, Kd_, ldsA[0], ldsB[0], tid); \
  for (int t = 0; t < nt_; ++t) { \
    const int cur = t & 1; \
    if (t + 1 < nt_) { \
      stage_w(Ap_ + (t + 1) * BK, Bp_ + (t + 1) * BK, Kd_, ldsA[cur ^ 1], ldsB[cur ^ 1], tid); \
      VMCNT4(); \
    } else { VMCNT0(); } \
    BARM(); \
    mfma_w(ldsA[cur], ldsB[cur], acc, wr, wc, lane); \
    LGKMD(); \
    BARM(); \
  } }

template <typename F>
__device__ __forceinline__ void epi_w(f32x4 acc[4][2], int wr, int wc, int lane, F f)
{
  const int quad = lane >> 4, l16 = lane & 15;
#pragma unroll
  for (int i = 0; i < 4; ++i)
#pragma unroll
    for (int j = 0; j < 2; ++j)
#pragma unroll
      for (int r = 0; r < 4; ++r)
        f(wr * 64 + i * 16 + quad * 4 + r, wc * 32 + j * 16 + l16, acc[i][j][r]);
}

// Bijective XCD swizzle for grid (4,14,16) = 896 blocks.
// xcd k <- (hh = k>>2, b-pair = k&3); per XCD: 2 z x 14 y x 4 x = 112 blocks.
// A-panel (z,bx): all 14 y-sharers co-XCD; B-panel (hh): on 4 XCDs. (r1->r2 FETCH proof.)
__device__ __forceinline__ void swz896(int& bx, int& by, int& bz)
{
  int lid = blockIdx.x + 4 * (blockIdx.y + 14 * blockIdx.z);
  int xcd = lid & 7, s = lid >> 3;        // s in [0,112)
  int zin = s / 56, s2 = s % 56;
  bx = s2 / 14;
  by = s2 % 14;
  bz = (xcd >> 2) * 8 + (xcd & 3) * 2 + zin;
}

// ---------------- small kernels -----------------------------------------------------------

__global__ void zstats_k(float* s)
{
  if (threadIdx.x < 64) s[threadIdx.x] = 0.f;
}

// transpose-convert: in f32 [Z][R][C] -> out bf16 [Z][C][R]
__global__ __launch_bounds__(256) void tconv_k(const float* __restrict__ in,
                                               bf16_t* __restrict__ out, int R, int Cc)
{
  __shared__ float tile[32][33];
  const long base = (long)blockIdx.z * R * Cc;
  const int c0 = blockIdx.x * 32, r0 = blockIdx.y * 32;
  const int tx = threadIdx.x & 31, ty = threadIdx.x >> 5;
#pragma unroll
  for (int i = 0; i < 4; ++i)
    tile[ty + i * 8][tx] = in[base + (long)(r0 + ty + i * 8) * Cc + c0 + tx];
  __syncthreads();
#pragma unroll
  for (int i = 0; i < 4; ++i)
    out[base + (long)(c0 + ty + i * 8) * R + r0 + tx] = (bf16_t)tile[tx][ty + i * 8];
}

// transpose bf16 [Z][R][C] -> bf16 [Z][C][R]
__global__ __launch_bounds__(256) void tconv_bf_k(const bf16_t* __restrict__ in,
                                                  bf16_t* __restrict__ out, int R, int Cc)
{
  __shared__ float tile[32][33];
  const long base = (long)blockIdx.z * R * Cc;
  const int c0 = blockIdx.x * 32, r0 = blockIdx.y * 32;
  const int tx = threadIdx.x & 31, ty = threadIdx.x >> 5;
#pragma unroll
  for (int i = 0; i < 4; ++i)
    tile[ty + i * 8][tx] = (float)in[base + (long)(r0 + ty + i * 8) * Cc + c0 + tx];
  __syncthreads();
#pragma unroll
  for (int i = 0; i < 4; ++i)
    out[base + (long)(c0 + ty + i * 8) * R + r0 + tx] = (bf16_t)tile[tx][ty + i * 8];
}

// f32 -> bf16 cast (no transpose), n multiple of 1024
__global__ __launch_bounds__(256) void cast_k(const float* __restrict__ in,
                                              bf16_t* __restrict__ out, long n)
{
  long i = ((long)blockIdx.x * 256 + threadIdx.x) * 4;
  if (i + 3 < n) {
    float4 v = *(const float4*)(in + i);
    out[i] = (bf16_t)v.x; out[i + 1] = (bf16_t)v.y;
    out[i + 2] = (bf16_t)v.z; out[i + 3] = (bf16_t)v.w;
  }
}

// Msum fold: O[i] = M[i] + M[SLICE + i]  (SLICE = 8*512*1792 elems)
__global__ __launch_bounds__(256) void msum_add_k(const bf16_t* __restrict__ M,
                                                  bf16_t* __restrict__ O)
{
  const long SLICE = (long)8 * CC2 * KVD;
  long i = ((long)blockIdx.x * 256 + threadIdx.x) * 8;
  bf16x8 x = *(const bf16x8*)(M + i);
  bf16x8 y = *(const bf16x8*)(M + SLICE + i);
  bf16x8 r;
#pragma unroll
  for (int j = 0; j < 8; ++j) r[j] = (bf16_t)((float)x[j] + (float)y[j]);
  *(bf16x8*)(O + i) = r;
}

// fused LN(emb2) and LN(concat(emb1,emb2,emb3)), bf16 outputs
__global__ __launch_bounds__(256) void ln_concat_k(const float* __restrict__ e1,
                                                   const float* __restrict__ e2,
                                                   const float* __restrict__ e3,
                                                   const float* __restrict__ g1,
                                                   const float* __restrict__ b1,
                                                   const float* __restrict__ ga,
                                                   const float* __restrict__ ba,
                                                   bf16_t* __restrict__ cxln,
                                                   bf16_t* __restrict__ embln)
{
  const long row = blockIdx.x;
  const float* p1 = e1 + row * 256;
  const float* p2 = e2 + row * 512;
  const float* p3 = e3 + row * 1024;
  const int t = threadIdx.x;
  float vals[7];
  float sa = 0.f, qa = 0.f;
#pragma unroll
  for (int i = 0; i < 7; ++i) {
    int idx = t + i * 256;
    float x = (idx < 256) ? p1[idx] : (idx < 768 ? p2[idx - 256] : p3[idx - 768]);
    vals[i] = x;
    sa += x; qa += x * x;
  }
  float s2 = vals[1] + vals[2];
  float q2 = vals[1] * vals[1] + vals[2] * vals[2];
  for (int off = 32; off; off >>= 1) {
    sa += __shfl_down(sa, off, 64); qa += __shfl_down(qa, off, 64);
    s2 += __shfl_down(s2, off, 64); q2 += __shfl_down(q2, off, 64);
  }
  __shared__ float red[4][4];
  const int wave = t >> 6, lane = t & 63;
  if (lane == 0) { red[0][wave] = sa; red[1][wave] = qa; red[2][wave] = s2; red[3][wave] = q2; }
  __syncthreads();
  float SA = red[0][0] + red[0][1] + red[0][2] + red[0][3];
  float QA = red[1][0] + red[1][1] + red[1][2] + red[1][3];
  float S2 = red[2][0] + red[2][1] + red[2][2] + red[2][3];
  float Q2 = red[3][0] + red[3][1] + red[3][2] + red[3][3];
  float ma = SA * (1.f / 1792.f);
  float va = QA * (1.f / 1792.f) - ma * ma;
  float rsa = rsqrtf(va + 1e-6f);
  float m2 = S2 * (1.f / 512.f);
  float v2 = Q2 * (1.f / 512.f) - m2 * m2;
  float rs2 = rsqrtf(v2 + 1e-6f);
#pragma unroll
  for (int i = 0; i < 7; ++i) {
    int idx = t + i * 256;
    embln[row * 1792 + idx] = (bf16_t)((vals[i] - ma) * rsa * ga[idx] + ba[idx]);
  }
  cxln[row * 512 + t]       = (bf16_t)((vals[1] - m2) * rs2 * g1[t] + b1[t]);
  cxln[row * 512 + t + 256] = (bf16_t)((vals[2] - m2) * rs2 * g1[t + 256] + b1[t + 256]);
}

// plain LN over 512 (fp32 in -> bf16 out)
__global__ __launch_bounds__(256) void ln2_k(const float* __restrict__ X,
                                             const float* __restrict__ g,
                                             const float* __restrict__ bb,
                                             bf16_t* __restrict__ Y)
{
  const long row = blockIdx.x;
  const float* p = X + row * 512;
  const int t = threadIdx.x;
  float x0 = p[t], x1 = p[t + 256];
  float s = x0 + x1, q = x0 * x0 + x1 * x1;
  for (int off = 32; off; off >>= 1) {
    s += __shfl_down(s, off, 64); q += __shfl_down(q, off, 64);
  }
  __shared__ float red[2][4];
  const int wave = t >> 6, lane = t & 63;
  if (lane == 0) { red[0][wave] = s; red[1][wave] = q; }
  __syncthreads();
  float S = red[0][0] + red[0][1] + red[0][2] + red[0][3];
  float Q = red[1][0] + red[1][1] + red[1][2] + red[1][3];
  float m = S * (1.f / 512.f);
  float v = Q * (1.f / 512.f) - m * m;
  float rs = rsqrtf(v + 1e-6f);
  Y[row * 512 + t]       = (bf16_t)((x0 - m) * rs * g[t] + bb[t]);
  Y[row * 512 + t + 256] = (bf16_t)((x1 - m) * rs * g[t + 256] + bb[t + 256]);
}

// softmax over last dim (1792), with instance-norm scale (shift-invariant), in place on bf16
__global__ __launch_bounds__(256) void softmax_k(bf16_t* __restrict__ SC,
                                                 const float* __restrict__ stats)
{
  const long rowid = blockIdx.x;          // z*512 + c
  const int z = (int)(rowid >> 9);
  const float inv_cnt = 1.f / (512.f * 1792.f);
  float m = stats[2 * z] * inv_cnt;
  float var = stats[2 * z + 1] * inv_cnt - m * m;
  float rs = rsqrtf(var + 1e-5f);
  bf16_t* rowp = SC + rowid * 1792;
  const int t = threadIdx.x;
  float v[7];
  float mx = -1e30f;
#pragma unroll
  for (int i = 0; i < 7; ++i) {
    v[i] = (float)rowp[t + i * 256] * rs;
    mx = fmaxf(mx, v[i]);
  }
  for (int off = 32; off; off >>= 1) mx = fmaxf(mx, __shfl_down(mx, off, 64));
  __shared__ float red[8];
  const int wave = t >> 6, lane = t & 63;
  if (lane == 0) red[wave] = mx;
  __syncthreads();
  mx = fmaxf(fmaxf(red[0], red[1]), fmaxf(red[2], red[3]));
  float sum = 0.f;
#pragma unroll
  for (int i = 0; i < 7; ++i) { v[i] = __expf(v[i] - mx); sum += v[i]; }
  for (int off = 32; off; off >>= 1) sum += __shfl_down(sum, off, 64);
  if (lane == 0) red[4 + wave] = sum;
  __syncthreads();
  float inv = 1.f / (red[4] + red[5] + red[6] + red[7]);
#pragma unroll
  for (int i = 0; i < 7; ++i) rowp[t + i * 256] = (bf16_t)(v[i] * inv);
}

// ---------------- GEMM kernels ------------------------------------------------------------

// generic 128-core: C[z][m][n] = sum_k A[z][m][k] B[z][n][k]
__global__ __launch_bounds__(256) void gemm_ab(const bf16_t* __restrict__ A, long astride,
                                               const bf16_t* __restrict__ B, long bstride,
                                               bf16_t* __restrict__ C, long cstride,
                                               int K, int ldc)
{
  const int z = blockIdx.z;
  GEMM_PROLOG();
  const bf16_t* Ap = A + z * astride + (long)blockIdx.x * 128 * K;
  const bf16_t* Bp = B + z * bstride + (long)blockIdx.y * 128 * K;
  GEMM_LOOP(Ap, Bp, K);
  bf16_t* Cb = C + (long)z * cstride;
  const int rbase = blockIdx.x * 128, cbase = blockIdx.y * 128;
  epilogue_apply(acc, wr, wc, lane, [&](int rr, int cc, float v) {
    Cb[(long)(rbase + rr) * ldc + cbase + cc] = (bf16_t)v;
  });
}

// T1[z][c2][c] = sum_e WqT[hh][c2][e] Gt[b][c][e]   (w-core, XCD-swizzled)
__global__ __launch_bounds__(512, 4) void gemm_t1_w(const bf16_t* __restrict__ WqT,
                                                    const bf16_t* __restrict__ Gt,
                                                    bf16_t* __restrict__ T1)
{
  int bxx, byy, bzz;
  swz896(bxx, byy, bzz);
  const int z = bzz, hh = z >> 3, b = z & 7;
  GEMMW_PROLOG();
  const bf16_t* Ap0 = WqT + (long)hh * CC2 * CC2 + (long)bxx * 128 * CC2;
  const bf16_t* Bp0 = Gt + (long)b * KVD * CC2 + (long)byy * 128 * CC2;
  GEMMW_LOOP(Ap0, Bp0, CC2);
  bf16_t* Cb = T1 + (long)z * CC2 * KVD;
  const int rbase = bxx * 128, cbase = byy * 128;
  epi_w(acc, wr, wc, lane, [&](int rr, int cc, float v) {
    Cb[(long)(rbase + rr) * KVD + cbase + cc] = (bf16_t)v;
  });
}

// scores: SC[z][c2][d] = sum_c T1[z][c2][c] WkT[hh][d][c] / sqrt(KV); + per-z sum/sumsq
__global__ __launch_bounds__(512, 4) void gemm_scores_w(const bf16_t* __restrict__ T1,
                                                        const bf16_t* __restrict__ WkT,
                                                        bf16_t* __restrict__ SC,
                                                        float* __restrict__ stats)
{
  int bxx, byy, bzz;
  swz896(bxx, byy, bzz);
  const int z = bzz, hh = z >> 3;
  GEMMW_PROLOG();
  const bf16_t* Ap0 = T1 + (long)z * CC2 * KVD + (long)bxx * 128 * KVD;
  const bf16_t* Bp0 = WkT + (long)hh * KVD * KVD + (long)byy * 128 * KVD;
  GEMMW_LOOP(Ap0, Bp0, KVD);
  const float scale = 0.02362277854f;  // 1/sqrt(1792)
  bf16_t* Cb = SC + (long)z * CC2 * KVD;
  const int rbase = bxx * 128, cbase = byy * 128;
  float s = 0.f, q = 0.f;
  epi_w(acc, wr, wc, lane, [&](int rr, int cc, float v) {
    v *= scale;
    Cb[(long)(rbase + rr) * KVD + cbase + cc] = (bf16_t)v;
    s += v; q += v * v;
  });
  for (int off = 32; off; off >>= 1) { s += __shfl_down(s, off, 64); q += __shfl_down(q, off, 64); }
  if (lane == 0) { sred[wave] = s; sred[8 + wave] = q; }
  __syncthreads();
  if (tid == 0) {
    float S = 0.f, Q = 0.f;
#pragma unroll
    for (int w = 0; w < 8; ++w) { S += sred[w]; Q += sred[8 + w]; }
    atomicAdd(&stats[2 * z], S);
    atomicAdd(&stats[2 * z + 1], Q);
  }
}

// Msum[z][c2][c] (+)= 0.25 * sum_d P[z][c2][d] WvB[hh][c][d]
__global__ __launch_bounds__(512, 4) void gemm_macc_w(const bf16_t* __restrict__ P,
                                                      const bf16_t* __restrict__ WvB,
                                                      bf16_t* __restrict__ M, int first)
{
  int bxx, byy, bzz;
  swz896(bxx, byy, bzz);
  const int z = bzz, hh = z >> 3;
  GEMMW_PROLOG();
  const bf16_t* Ap0 = P + (long)z * CC2 * KVD + (long)bxx * 128 * KVD;
  const bf16_t* Bp0 = WvB + (long)hh * KVD * KVD + (long)byy * 128 * KVD;
  GEMMW_LOOP(Ap0, Bp0, KVD);
  bf16_t* Cb = M + (long)z * CC2 * KVD;
  const int rbase = bxx * 128, cbase = byy * 128;
  epi_w(acc, wr, wc, lane, [&](int rr, int cc, float v) {
    long idx = (long)(rbase + rr) * KVD + cbase + cc;
    float prev = first ? 0.f : (float)Cb[idx];
    Cb[idx] = (bf16_t)(prev + v * 0.25f);
  });
}

// ctx[b][n][c2] = sum_c E[b][n][c] Msum8[b][c2][c]   (Msum8 = head-pair-folded)
__global__ __launch_bounds__(256) void gemm_ctx(const bf16_t* __restrict__ E,
                                                const bf16_t* __restrict__ Msum8,
                                                bf16_t* __restrict__ CTX)
{
  const int b = blockIdx.z;
  GEMM_PROLOG();
  const bf16_t* Ap = E + (long)b * NTOK * KVD + (long)blockIdx.x * 128 * KVD;
  const bf16_t* Bp = Msum8 + (long)b * CC2 * KVD + (long)blockIdx.y * 128 * KVD;
  GEMM_LOOP(Ap, Bp, KVD);
  bf16_t* Cb = CTX + (long)b * NTOK * CC2;
  const int rbase = blockIdx.x * 128, cbase = blockIdx.y * 128;
  epilogue_apply(acc, wr, wc, lane, [&](int rr, int cc, float v) {
    Cb[(long)(rbase + rr) * CC2 + cbase + cc] = (bf16_t)v;
  });
}

// o-proj + residual: CX2 = CTX@WOT^T + emb2 (fp32 out)
__global__ __launch_bounds__(256) void gemm_resid(const bf16_t* __restrict__ A,
                                                  const bf16_t* __restrict__ B,
                                                  const float* __restrict__ emb2,
                                                  float* __restrict__ CX2)
{
  GEMM_PROLOG();
  const bf16_t* Ap = A + (long)blockIdx.x * 128 * CC2;
  const bf16_t* Bp = B + (long)blockIdx.y * 128 * CC2;
  GEMM_LOOP(Ap, Bp, CC2);
  const int rbase = blockIdx.x * 128, cbase = blockIdx.y * 128;
  epilogue_apply(acc, wr, wc, lane, [&](int rr, int cc, float v) {
    long idx = (long)(rbase + rr) * CC2 + cbase + cc;
    CX2[idx] = v + emb2[idx];
  });
}

// fc1 + bias + exact gelu -> bf16 (w-core)
__global__ __launch_bounds__(512, 4) void gemm_gelu_w(const bf16_t* __restrict__ A,
                                                      const bf16_t* __restrict__ B,
                                                      const float* __restrict__ bias,
                                                      bf16_t* __restrict__ H)
{
  GEMMW_PROLOG();
  const bf16_t* Ap0 = A + (long)blockIdx.x * 128 * CC2;
  const bf16_t* Bp0 = B + (long)blockIdx.y * 128 * CC2;
  GEMMW_LOOP(Ap0, Bp0, CC2);
  const int rbase = blockIdx.x * 128, cbase = blockIdx.y * 128;
  epi_w(acc, wr, wc, lane, [&](int rr, int cc, float v) {
    float x = v + bias[cbase + cc];
    float g = 0.5f * x * (1.0f + erff(x * 0.70710678118f));
    H[(long)(rbase + rr) * FFD + cbase + cc] = (bf16_t)g;
  });
}

// fc2 + bias + residual -> fp32 out
__global__ __launch_bounds__(256) void gemm_out(const bf16_t* __restrict__ A,
                                                const bf16_t* __restrict__ B,
                                                const float* __restrict__ bias,
                                                const float* __restrict__ CX2,
                                                float* __restrict__ OUT)
{
  GEMM_PROLOG();
  const bf16_t* Ap = A + (long)blockIdx.x * 128 * FFD;
  const bf16_t* Bp = B + (long)blockIdx.y * 128 * FFD;
  GEMM_LOOP(Ap, Bp, FFD);
  const int rbase = blockIdx.x * 128, cbase = blockIdx.y * 128;
  epilogue_apply(acc, wr, wc, lane, [&](int rr, int cc, float v) {
    long idx = (long)(rbase + rr) * CC2 + cbase + cc;
    OUT[idx] = v + bias[cbase + cc] + CX2[idx];
  });
}

// ---------------- host launcher -----------------------------------------------------------

extern "C" void kernel_launch(void* const* d_in, const int* in_sizes, int n_in,
                              void* d_out, int out_size, void* d_ws, size_t ws_size,
                              hipStream_t stream)
{
  const float* emb1   = (const float*)d_in[0];
  const float* emb2   = (const float*)d_in[1];
  const float* emb3   = (const float*)d_in[2];
  const float* Wq     = (const float*)d_in[3];
  const float* Wk     = (const float*)d_in[4];
  const float* Wv     = (const float*)d_in[5];
  const float* Wout   = (const float*)d_in[6];
  const float* ln1_g  = (const float*)d_in[7];
  const float* ln1_b  = (const float*)d_in[8];
  const float* lnall_g = (const float*)d_in[9];
  const float* lnall_b = (const float*)d_in[10];
  const float* lnffn_g = (const float*)d_in[11];
  const float* lnffn_b = (const float*)d_in[12];
  const float* fc1_w  = (const float*)d_in[13];
  const float* fc1_b  = (const float*)d_in[14];
  const float* fc2_w  = (const float*)d_in[15];
  const float* fc2_b  = (const float*)d_in[16];
  float* out = (float*)d_out;
  (void)in_sizes; (void)n_in; (void)out_size; (void)ws_size;

  char* ws = (char*)d_ws;
  size_t off = 0;
  auto alloc = [&](size_t bytes) {
    size_t r = off;
    off = (off + bytes + 255) & ~(size_t)255;
    return r;
  };

  // persistent buffers (~103 MiB)
  size_t oEMBLN = alloc((size_t)ROWS * KVD * 2);
  size_t oCXLN  = alloc((size_t)ROWS * CC2 * 2);
  size_t oCX2   = alloc((size_t)ROWS * CC2 * 4);
  size_t oGt    = alloc((size_t)BSZ * KVD * CC2 * 2);
  size_t oMsum  = alloc((size_t)16 * CC2 * KVD * 2);
  size_t oWOT   = alloc((size_t)CC2 * CC2 * 2);
  size_t oF1T   = alloc((size_t)FFD * CC2 * 2);
  size_t oF2T   = alloc((size_t)CC2 * FFD * 2);
  size_t oSTATS = alloc(64 * 4);
  // scratch region (~84 MiB peak), phase-aliased
  size_t oSCR   = alloc(0);
  size_t oCXLNT  = alloc((size_t)BSZ * CC2 * NTOK * 2);   // phase A
  size_t oEMBLNT = alloc((size_t)BSZ * KVD * NTOK * 2);

  bf16_t* EMBLN  = (bf16_t*)(ws + oEMBLN);
  bf16_t* CXLN   = (bf16_t*)(ws + oCXLN);
  float*  CX2    = (float*)(ws + oCX2);
  bf16_t* Gt     = (bf16_t*)(ws + oGt);
  bf16_t* Msum   = (bf16_t*)(ws + oMsum);
  bf16_t* WOT    = (bf16_t*)(ws + oWOT);
  bf16_t* F1T    = (bf16_t*)(ws + oF1T);
  bf16_t* F2T    = (bf16_t*)(ws + oF2T);
  float*  STATS  = (float*)(ws + oSTATS);
  bf16_t* CXLNT  = (bf16_t*)(ws + oCXLNT);
  bf16_t* EMBLNT = (bf16_t*)(ws + oEMBLNT);
  // phase B (head-pair loop) aliases scratch: WqT 1 + WkT 12.25 + WvB 12.25 + T1 28 + SC 28 MiB
  char* scr = ws + oSCR;
  auto rnd = [](size_t v) { return (v + 255) & ~(size_t)255; };
  bf16_t* WqT = (bf16_t*)(scr);
  bf16_t* WkT = (bf16_t*)(scr + rnd((size_t)2 * CC2 * CC2 * 2));
  bf16_t* WvB = (bf16_t*)((char*)WkT + rnd((size_t)2 * KVD * KVD * 2));
  bf16_t* T1  = (bf16_t*)((char*)WvB + rnd((size_t)2 * KVD * KVD * 2));
  bf16_t* SC  = (bf16_t*)((char*)T1 + rnd((size_t)16 * CC2 * KVD * 2));
  // phase C aliases scratch: Msum8 (14.7) then CTX (8.4) then FFNH (33.5)
  bf16_t* Msum8 = (bf16_t*)(scr);
  bf16_t* CTX   = (bf16_t*)(scr + rnd((size_t)8 * CC2 * KVD * 2));
  bf16_t* FFNH  = (bf16_t*)((char*)CTX + rnd((size_t)ROWS * CC2 * 2));
  bf16_t* X2LN = CXLN;  // ffn-LN aliases cxln (dead after transposes)

  // stats zero + global weight transpose-converts
  zstats_k<<<1, 64, 0, stream>>>(STATS);
  tconv_k<<<dim3(16, 16), 256, 0, stream>>>(Wout, WOT, 512, 512);
  tconv_k<<<dim3(64, 16), 256, 0, stream>>>(fc1_w, F1T, 512, 2048);
  tconv_k<<<dim3(16, 64), 256, 0, stream>>>(fc2_w, F2T, 2048, 512);

  // fused layernorms -> bf16 activations
  ln_concat_k<<<8192, 256, 0, stream>>>(emb1, emb2, emb3, ln1_g, ln1_b,
                                        lnall_g, lnall_b, CXLN, EMBLN);

  // token-major transposes (once), then G^T[b][c][e] = sum_n E[n][c] CXLN[n][e]
  tconv_bf_k<<<dim3(16, 32, 8), 256, 0, stream>>>(CXLN, CXLNT, 1024, 512);
  tconv_bf_k<<<dim3(56, 32, 8), 256, 0, stream>>>(EMBLN, EMBLNT, 1024, 1792);
  gemm_ab<<<dim3(14, 4, 8), 256, 0, stream>>>(EMBLNT, (long)KVD * NTOK,
                                              CXLNT, (long)CC2 * NTOK,
                                              Gt, (long)KVD * CC2, NTOK, CC2);

  // attention, two heads per iteration (z = hh*8 + b, 16 batches per launch)
  for (int g = 0; g < 2; ++g) {
    tconv_k<<<dim3(16, 16, 2), 256, 0, stream>>>(Wq + (long)g * 2 * CC2 * CC2, WqT, 512, 512);
    tconv_k<<<dim3(56, 56, 2), 256, 0, stream>>>(Wk + (long)g * 2 * KVD * KVD, WkT, 1792, 1792);
    cast_k<<<6272, 256, 0, stream>>>(Wv + (long)g * 2 * KVD * KVD, WvB, (long)2 * KVD * KVD);

    gemm_t1_w<<<dim3(4, 14, 16), 512, 0, stream>>>(WqT, Gt, T1);
    gemm_scores_w<<<dim3(4, 14, 16), 512, 0, stream>>>(T1, WkT, SC, STATS + g * 32);
    softmax_k<<<8192, 256, 0, stream>>>(SC, STATS + g * 32);
    gemm_macc_w<<<dim3(4, 14, 16), 512, 0, stream>>>(SC, WvB, Msum, g == 0 ? 1 : 0);
  }

  // fold head-pairs, then ctx[b][n][c2] = E · Msum8[b]^T (single K=1792 pass)
  msum_add_k<<<3584, 256, 0, stream>>>(Msum, Msum8);
  gemm_ctx<<<dim3(8, 4, 8), 256, 0, stream>>>(EMBLN, Msum8, CTX);

  // o-proj + residual
  gemm_resid<<<dim3(64, 4), 256, 0, stream>>>(CTX, WOT, emb2, CX2);

  // FFN
  ln2_k<<<8192, 256, 0, stream>>>(CX2, lnffn_g, lnffn_b, X2LN);
  gemm_gelu_w<<<dim3(64, 16), 512, 0, stream>>>(X2LN, F1T, fc1_b, FFNH);
  gemm_out<<<dim3(64, 4), 256, 0, stream>>>(FFNH, F2T, fc2_b, CX2, out);
}

// Round 11
// 738.365 us; speedup vs baseline: 1.0551x; 1.0551x over previous
//
#include <hip/hip_runtime.h>
#include <cstdint>
#include <cmath>

typedef __bf16 bf16_t;
typedef __attribute__((ext_vector_type(8))) __bf16 bf16x8;
typedef __attribute__((ext_vector_type(4))) float f32x4;

#define AS_G(x) ((__attribute__((address_space(1))) void*)(x))
#define AS_L(x) ((__attribute__((address_space(3))) void*)(x))

#define BK 64

// problem constants
#define BSZ 8
#define NTOK 1024
#define CC2 512
#define KVD 1792
#define NH 4
#define FFD 2048
#define ROWS 8192  // B*N

// sync/wait primitives: asm with memory clobber so the compiler cannot hoist LDS
// reads above a gate barrier or sink DMA issues below it.
#define BARM()   asm volatile("s_barrier" ::: "memory")
#define VMCNT8() asm volatile("s_waitcnt vmcnt(8)" ::: "memory")
#define VMCNT4() asm volatile("s_waitcnt vmcnt(4)" ::: "memory")
#define VMCNT0() asm volatile("s_waitcnt vmcnt(0)" ::: "memory")
#define LGKMD()  asm volatile("s_waitcnt lgkmcnt(0)" ::: "memory")

// ---------------- 128x128 GEMM core (round-2 proven form: dbuf, counted vmcnt) ------------
// LDS layout: lds[r][slot] holds global[r][slot ^ (r&7)] in 16B chunks (8 bf16).
// Per tile: [stage t+1 -> other buf][vmcnt(8)][barrier][compute (compiler-scheduled)]
//           [lgkmcnt(0)][barrier].

__device__ __forceinline__ void stage_pair(const bf16_t* __restrict__ A,
                                           const bf16_t* __restrict__ B,
                                           int ld, bf16_t* ldsA, bf16_t* ldsB, int tid)
{
#pragma unroll
  for (int it = 0; it < 4; ++it) {
    int chunk = it * 256 + tid;          // 0..1023
    int r = chunk >> 3;                  // 0..127
    int s = chunk & 7;                   // lds slot (16B chunk)
    int cg = ((s ^ (r & 7)) << 3);       // swizzled global column (elements)
    __builtin_amdgcn_global_load_lds(AS_G(A + (long)r * ld + cg),
                                     AS_L(ldsA + chunk * 8), 16, 0, 0);
    __builtin_amdgcn_global_load_lds(AS_G(B + (long)r * ld + cg),
                                     AS_L(ldsB + chunk * 8), 16, 0, 0);
  }
}

__device__ __forceinline__ void mfma_step(const bf16_t* ldsA, const bf16_t* ldsB,
                                          f32x4 acc[4][4], int wr, int wc, int lane, int kc)
{
  const int quad = lane >> 4, l16 = lane & 15;
  bf16x8 a[4], b[4];
#pragma unroll
  for (int i = 0; i < 4; ++i) {
    int r = wr * 64 + i * 16 + l16;
    int slot = (kc + quad) ^ (r & 7);
    a[i] = *(const bf16x8*)(ldsA + r * BK + slot * 8);
  }
#pragma unroll
  for (int j = 0; j < 4; ++j) {
    int r = wc * 64 + j * 16 + l16;
    int slot = (kc + quad) ^ (r & 7);
    b[j] = *(const bf16x8*)(ldsB + r * BK + slot * 8);
  }
#pragma unroll
  for (int i = 0; i < 4; ++i)
#pragma unroll
    for (int j = 0; j < 4; ++j)
      acc[i][j] = __builtin_amdgcn_mfma_f32_16x16x32_bf16(a[i], b[j], acc[i][j], 0, 0, 0);
}

#define GEMM_PROLOG() \
  __shared__ __align__(16) bf16_t ldsA[2][128 * BK]; \
  __shared__ __align__(16) bf16_t ldsB[2][128 * BK]; \
  const int tid = threadIdx.x; \
  const int wave = tid >> 6, lane = tid & 63; \
  const int wr = wave >> 1, wc = wave & 1; \
  f32x4 acc[4][4] = {};

#define GEMM_LOOP(Aptr, Bptr, Kdim) { \
  const bf16_t* Ap_ = (Aptr); const bf16_t* Bp_ = (Bptr); const int Kd_ = (Kdim); \
  const int nt_ = Kd_ / BK; \
  stage_pair(Ap_, Bp_, Kd_, ldsA[0], ldsB[0], tid); \
  for (int t = 0; t < nt_; ++t) { \
    const int cur = t & 1; \
    if (t + 1 < nt_) { \
      stage_pair(Ap_ + (t + 1) * BK, Bp_ + (t + 1) * BK, Kd_, ldsA[cur ^ 1], ldsB[cur ^ 1], tid); \
      VMCNT8(); \
    } else { VMCNT0(); } \
    BARM(); \
    mfma_step(ldsA[cur], ldsB[cur], acc, wr, wc, lane, 0); \
    mfma_step(ldsA[cur], ldsB[cur], acc, wr, wc, lane, 4); \
    LGKMD(); \
    BARM(); \
  } }

template <typename F>
__device__ __forceinline__ void epilogue_apply(f32x4 acc[4][4], int wr, int wc, int lane, F f)
{
  const int quad = lane >> 4, l16 = lane & 15;
#pragma unroll
  for (int i = 0; i < 4; ++i)
#pragma unroll
    for (int j = 0; j < 4; ++j)
#pragma unroll
      for (int r = 0; r < 4; ++r)
        f(wr * 64 + i * 16 + quad * 4 + r, wc * 64 + j * 16 + l16, acc[i][j][r]);
}

// ---------------- 256x256 core (r3 single-region form + distributed staging) --------------
// Per K-tile: [issue EARLY half of t+1 (4 loads, rows 0-127)][vmcnt(4)][BAR]
//             [single compute region; LATE half of t+1 (rows 128-255) issued mid-region]
//             [lgkmcnt(0)][BAR].
// Gate proof: issue order ...E(t),L(t),E(t+1); vmcnt(4) leaves only E(t+1)'s 4 loads in
// flight -> L(t) (and all older) complete => tile t fully landed for every wave before the
// barrier. WAR: E/L(t+1) write buf^1 = tile t-1's buffer, whose reads were lgkm-drained
// before tile t-1's end barrier, which all waves passed.
// Best-measured configuration of the session (r7: 752.3 us total; macc 83 us).

__device__ __forceinline__ void stage256h(const bf16_t* __restrict__ A,
                                          const bf16_t* __restrict__ B,
                                          int ld, bf16_t* ldsA, bf16_t* ldsB, int tid, int h)
{
#pragma unroll
  for (int i = 0; i < 2; ++i) {
    int it = h * 2 + i;
    int chunk = it * 512 + tid;          // rows h*128 .. h*128+127
    int r = chunk >> 3;                  // 0..255
    int s = chunk & 7;
    int cg = ((s ^ (r & 7)) << 3);
    __builtin_amdgcn_global_load_lds(AS_G(A + (long)r * ld + cg),
                                     AS_L(ldsA + chunk * 8), 16, 0, 0);
    __builtin_amdgcn_global_load_lds(AS_G(B + (long)r * ld + cg),
                                     AS_L(ldsB + chunk * 8), 16, 0, 0);
  }
}

__device__ __forceinline__ void qread_a(const bf16_t* ldsOp, int wr, int rh, int lane,
                                        bf16x8 a[4][2])
{
  const int quad = lane >> 4, l16 = lane & 15;
#pragma unroll
  for (int mi = 0; mi < 4; ++mi)
#pragma unroll
    for (int kc = 0; kc < 2; ++kc) {
      int r = wr * 128 + rh * 64 + mi * 16 + l16;
      int slot = (kc * 4 + quad) ^ (r & 7);
      a[mi][kc] = *(const bf16x8*)(ldsOp + r * BK + slot * 8);
    }
}

__device__ __forceinline__ void qread_b(const bf16_t* ldsOp, int wc, int ch, int lane,
                                        bf16x8 b[2][2])
{
  const int quad = lane >> 4, l16 = lane & 15;
#pragma unroll
  for (int nj = 0; nj < 2; ++nj)
#pragma unroll
    for (int kc = 0; kc < 2; ++kc) {
      int r = wc * 64 + ch * 32 + nj * 16 + l16;
      int slot = (kc * 4 + quad) ^ (r & 7);
      b[nj][kc] = *(const bf16x8*)(ldsOp + r * BK + slot * 8);
    }
}

template <int RH, int CH>
__device__ __forceinline__ void mfma16(f32x4 acc[8][4], const bf16x8 a[4][2],
                                       const bf16x8 (&b)[2][2])
{
#pragma unroll
  for (int mi = 0; mi < 4; ++mi)
#pragma unroll
    for (int nj = 0; nj < 2; ++nj)
#pragma unroll
      for (int kc = 0; kc < 2; ++kc)
        acc[RH * 4 + mi][CH * 2 + nj] =
            __builtin_amdgcn_mfma_f32_16x16x32_bf16(a[mi][kc], b[nj][kc],
                                                    acc[RH * 4 + mi][CH * 2 + nj], 0, 0, 0);
}

#define GEMM256_PROLOG() \
  __shared__ __align__(16) bf16_t ldsA[2][256 * BK]; \
  __shared__ __align__(16) bf16_t ldsB[2][256 * BK]; \
  __shared__ float sred[16]; \
  (void)sred; \
  const int tid = threadIdx.x; \
  const int wave = tid >> 6, lane = tid & 63; \
  const int wr = wave >> 2, wc = wave & 3; \
  f32x4 acc[8][4] = {};

#define GEMM256_LOOP(Aptr, Bptr, Kdim) { \
  const bf16_t* Ap = (Aptr); const bf16_t* Bp = (Bptr); const int Kd = (Kdim); \
  const int nt = Kd / BK; \
  stage256h(Ap, Bp, Kd, ldsA[0], ldsB[0], tid, 0); \
  stage256h(Ap, Bp, Kd, ldsA[0], ldsB[0], tid, 1); \
  for (int t = 0; t < nt; ++t) { \
    const int cur = t & 1; \
    if (t + 1 < nt) { \
      stage256h(Ap + (t + 1) * BK, Bp + (t + 1) * BK, Kd, ldsA[cur ^ 1], ldsB[cur ^ 1], tid, 0); \
      VMCNT4(); \
    } else { VMCNT0(); } \
    BARM(); \
    { \
      bf16x8 a[4][2], b0[2][2], b1[2][2]; \
      qread_a(ldsA[cur], wr, 0, lane, a); \
      qread_b(ldsB[cur], wc, 0, lane, b0); \
      qread_b(ldsB[cur], wc, 1, lane, b1); \
      mfma16<0, 0>(acc, a, b0); \
      mfma16<0, 1>(acc, a, b1); \
      if (t + 1 < nt) \
        stage256h(Ap + (t + 1) * BK, Bp + (t + 1) * BK, Kd, ldsA[cur ^ 1], ldsB[cur ^ 1], tid, 1); \
      qread_a(ldsA[cur], wr, 1, lane, a); \
      mfma16<1, 0>(acc, a, b0); \
      mfma16<1, 1>(acc, a, b1); \
    } \
    LGKMD(); \
    BARM(); \
  } }

template <typename F>
__device__ __forceinline__ void epi256(f32x4 acc[8][4], int wr, int wc, int lane, F f)
{
  const int quad = lane >> 4, l16 = lane & 15;
#pragma unroll
  for (int i = 0; i < 8; ++i)
#pragma unroll
    for (int j = 0; j < 4; ++j)
#pragma unroll
      for (int r = 0; r < 4; ++r)
        f(wr * 128 + (i >> 2) * 64 + (i & 3) * 16 + quad * 4 + r,
          wc * 64 + (j >> 1) * 32 + (j & 1) * 16 + l16, acc[i][j][r]);
}

// XCD-locality swizzle for the attention GEMMs.
// mg=0: grid (2,7,16)=224 blocks, XCD k <- (hh=k>>2, b-pair=k&3)  [r1->r2: FETCH 122->54 MB]
// mg=1: grid (2,7,32)=448 blocks, XCD k <- (hh=k>>1, b-quad=k&1); both bijective.
__device__ __forceinline__ void swzA(int mg, int& bx, int& by, int& bz)
{
  int lid = blockIdx.x + 2 * (blockIdx.y + 7 * blockIdx.z);
  int xcd = lid & 7, s = lid >> 3;
  int y = s % 7, t = s / 7;              // mg=0: t in [0,4); mg=1: t in [0,8)
  bx = t & 1;
  by = y;
  if (mg) bz = (xcd >> 1) * 8 + (xcd & 1) * 4 + (t >> 1);
  else    bz = (xcd >> 2) * 8 + (xcd & 3) * 2 + (t >> 1);
}

// ---------------- small kernels -----------------------------------------------------------

__global__ void zstats_k(float* s)
{
  if (threadIdx.x < 64) s[threadIdx.x] = 0.f;
}

// transpose-convert: in f32 [Z][R][C] -> out bf16 [Z][C][R]
__global__ __launch_bounds__(256) void tconv_k(const float* __restrict__ in,
                                               bf16_t* __restrict__ out, int R, int Cc)
{
  __shared__ float tile[32][33];
  const long base = (long)blockIdx.z * R * Cc;
  const int c0 = blockIdx.x * 32, r0 = blockIdx.y * 32;
  const int tx = threadIdx.x & 31, ty = threadIdx.x >> 5;
#pragma unroll
  for (int i = 0; i < 4; ++i)
    tile[ty + i * 8][tx] = in[base + (long)(r0 + ty + i * 8) * Cc + c0 + tx];
  __syncthreads();
#pragma unroll
  for (int i = 0; i < 4; ++i)
    out[base + (long)(c0 + ty + i * 8) * R + r0 + tx] = (bf16_t)tile[tx][ty + i * 8];
}

// transpose bf16 [Z][R][C] -> bf16 [Z][C][R]
__global__ __launch_bounds__(256) void tconv_bf_k(const bf16_t* __restrict__ in,
                                                  bf16_t* __restrict__ out, int R, int Cc)
{
  __shared__ float tile[32][33];
  const long base = (long)blockIdx.z * R * Cc;
  const int c0 = blockIdx.x * 32, r0 = blockIdx.y * 32;
  const int tx = threadIdx.x & 31, ty = threadIdx.x >> 5;
#pragma unroll
  for (int i = 0; i < 4; ++i)
    tile[ty + i * 8][tx] = (float)in[base + (long)(r0 + ty + i * 8) * Cc + c0 + tx];
  __syncthreads();
#pragma unroll
  for (int i = 0; i < 4; ++i)
    out[base + (long)(c0 + ty + i * 8) * R + r0 + tx] = (bf16_t)tile[tx][ty + i * 8];
}

// f32 -> bf16 cast (no transpose), n multiple of 1024
__global__ __launch_bounds__(256) void cast_k(const float* __restrict__ in,
                                              bf16_t* __restrict__ out, long n)
{
  long i = ((long)blockIdx.x * 256 + threadIdx.x) * 4;
  if (i + 3 < n) {
    float4 v = *(const float4*)(in + i);
    out[i] = (bf16_t)v.x; out[i + 1] = (bf16_t)v.y;
    out[i + 2] = (bf16_t)v.z; out[i + 3] = (bf16_t)v.w;
  }
}

// Msum fold: O[i] = sum_{h<nfold} M[h*SLICE + i]  (SLICE = 8*512*1792 elems)
__global__ __launch_bounds__(256) void msum_add_k(const bf16_t* __restrict__ M,
                                                  bf16_t* __restrict__ O, int nfold)
{
  const long SLICE = (long)8 * CC2 * KVD;
  long i = ((long)blockIdx.x * 256 + threadIdx.x) * 8;
  float acc[8] = {};
  for (int h = 0; h < nfold; ++h) {
    bf16x8 x = *(const bf16x8*)(M + h * SLICE + i);
#pragma unroll
    for (int j = 0; j < 8; ++j) acc[j] += (float)x[j];
  }
  bf16x8 r;
#pragma unroll
  for (int j = 0; j < 8; ++j) r[j] = (bf16_t)acc[j];
  *(bf16x8*)(O + i) = r;
}

// fused LN(emb2) and LN(concat(emb1,emb2,emb3)), bf16 outputs
__global__ __launch_bounds__(256) void ln_concat_k(const float* __restrict__ e1,
                                                   const float* __restrict__ e2,
                                                   const float* __restrict__ e3,
                                                   const float* __restrict__ g1,
                                                   const float* __restrict__ b1,
                                                   const float* __restrict__ ga,
                                                   const float* __restrict__ ba,
                                                   bf16_t* __restrict__ cxln,
                                                   bf16_t* __restrict__ embln)
{
  const long row = blockIdx.x;
  const float* p1 = e1 + row * 256;
  const float* p2 = e2 + row * 512;
  const float* p3 = e3 + row * 1024;
  const int t = threadIdx.x;
  float vals[7];
  float sa = 0.f, qa = 0.f;
#pragma unroll
  for (int i = 0; i < 7; ++i) {
    int idx = t + i * 256;
    float x = (idx < 256) ? p1[idx] : (idx < 768 ? p2[idx - 256] : p3[idx - 768]);
    vals[i] = x;
    sa += x; qa += x * x;
  }
  float s2 = vals[1] + vals[2];
  float q2 = vals[1] * vals[1] + vals[2] * vals[2];
  for (int off = 32; off; off >>= 1) {
    sa += __shfl_down(sa, off, 64); qa += __shfl_down(qa, off, 64);
    s2 += __shfl_down(s2, off, 64); q2 += __shfl_down(q2, off, 64);
  }
  __shared__ float red[4][4];
  const int wave = t >> 6, lane = t & 63;
  if (lane == 0) { red[0][wave] = sa; red[1][wave] = qa; red[2][wave] = s2; red[3][wave] = q2; }
  __syncthreads();
  float SA = red[0][0] + red[0][1] + red[0][2] + red[0][3];
  float QA = red[1][0] + red[1][1] + red[1][2] + red[1][3];
  float S2 = red[2][0] + red[2][1] + red[2][2] + red[2][3];
  float Q2 = red[3][0] + red[3][1] + red[3][2] + red[3][3];
  float ma = SA * (1.f / 1792.f);
  float va = QA * (1.f / 1792.f) - ma * ma;
  float rsa = rsqrtf(va + 1e-6f);
  float m2 = S2 * (1.f / 512.f);
  float v2 = Q2 * (1.f / 512.f) - m2 * m2;
  float rs2 = rsqrtf(v2 + 1e-6f);
#pragma unroll
  for (int i = 0; i < 7; ++i) {
    int idx = t + i * 256;
    embln[row * 1792 + idx] = (bf16_t)((vals[i] - ma) * rsa * ga[idx] + ba[idx]);
  }
  cxln[row * 512 + t]       = (bf16_t)((vals[1] - m2) * rs2 * g1[t] + b1[t]);
  cxln[row * 512 + t + 256] = (bf16_t)((vals[2] - m2) * rs2 * g1[t + 256] + b1[t + 256]);
}

// plain LN over 512 (fp32 in -> bf16 out)
__global__ __launch_bounds__(256) void ln2_k(const float* __restrict__ X,
                                             const float* __restrict__ g,
                                             const float* __restrict__ bb,
                                             bf16_t* __restrict__ Y)
{
  const long row = blockIdx.x;
  const float* p = X + row * 512;
  const int t = threadIdx.x;
  float x0 = p[t], x1 = p[t + 256];
  float s = x0 + x1, q = x0 * x0 + x1 * x1;
  for (int off = 32; off; off >>= 1) {
    s += __shfl_down(s, off, 64); q += __shfl_down(q, off, 64);
  }
  __shared__ float red[2][4];
  const int wave = t >> 6, lane = t & 63;
  if (lane == 0) { red[0][wave] = s; red[1][wave] = q; }
  __syncthreads();
  float S = red[0][0] + red[0][1] + red[0][2] + red[0][3];
  float Q = red[1][0] + red[1][1] + red[1][2] + red[1][3];
  float m = S * (1.f / 512.f);
  float v = Q * (1.f / 512.f) - m * m;
  float rs = rsqrtf(v + 1e-6f);
  Y[row * 512 + t]       = (bf16_t)((x0 - m) * rs * g[t] + bb[t]);
  Y[row * 512 + t + 256] = (bf16_t)((x1 - m) * rs * g[t + 256] + bb[t + 256]);
}

// softmax over last dim (1792), with instance-norm scale (shift-invariant), in place on bf16
__global__ __launch_bounds__(256) void softmax_k(bf16_t* __restrict__ SC,
                                                 const float* __restrict__ stats)
{
  const long rowid = blockIdx.x;          // z*512 + c
  const int z = (int)(rowid >> 9);
  const float inv_cnt = 1.f / (512.f * 1792.f);
  float m = stats[2 * z] * inv_cnt;
  float var = stats[2 * z + 1] * inv_cnt - m * m;
  float rs = rsqrtf(var + 1e-5f);
  bf16_t* rowp = SC + rowid * 1792;
  const int t = threadIdx.x;
  float v[7];
  float mx = -1e30f;
#pragma unroll
  for (int i = 0; i < 7; ++i) {
    v[i] = (float)rowp[t + i * 256] * rs;
    mx = fmaxf(mx, v[i]);
  }
  for (int off = 32; off; off >>= 1) mx = fmaxf(mx, __shfl_down(mx, off, 64));
  __shared__ float red[8];
  const int wave = t >> 6, lane = t & 63;
  if (lane == 0) red[wave] = mx;
  __syncthreads();
  mx = fmaxf(fmaxf(red[0], red[1]), fmaxf(red[2], red[3]));
  float sum = 0.f;
#pragma unroll
  for (int i = 0; i < 7; ++i) { v[i] = __expf(v[i] - mx); sum += v[i]; }
  for (int off = 32; off; off >>= 1) sum += __shfl_down(sum, off, 64);
  if (lane == 0) red[4 + wave] = sum;
  __syncthreads();
  float inv = 1.f / (red[4] + red[5] + red[6] + red[7]);
#pragma unroll
  for (int i = 0; i < 7; ++i) rowp[t + i * 256] = (bf16_t)(v[i] * inv);
}

// ---------------- GEMM kernels ------------------------------------------------------------

// generic 128-core: C[z][m][n] = sum_k A[z][m][k] B[z][n][k]
__global__ __launch_bounds__(256) void gemm_ab(const bf16_t* __restrict__ A, long astride,
                                               const bf16_t* __restrict__ B, long bstride,
                                               bf16_t* __restrict__ C, long cstride,
                                               int K, int ldc)
{
  const int z = blockIdx.z;
  GEMM_PROLOG();
  const bf16_t* Ap = A + z * astride + (long)blockIdx.x * 128 * K;
  const bf16_t* Bp = B + z * bstride + (long)blockIdx.y * 128 * K;
  GEMM_LOOP(Ap, Bp, K);
  bf16_t* Cb = C + (long)z * cstride;
  const int rbase = blockIdx.x * 128, cbase = blockIdx.y * 128;
  epilogue_apply(acc, wr, wc, lane, [&](int rr, int cc, float v) {
    Cb[(long)(rbase + rr) * ldc + cbase + cc] = (bf16_t)v;
  });
}

// T1[z][c2][c] = sum_e WqT[hh][c2][e] Gt[b][c][e]   (256-core, XCD-swizzled)
__global__ __launch_bounds__(512, 2) void gemm_t1_256(const bf16_t* __restrict__ WqT,
                                                      const bf16_t* __restrict__ Gt,
                                                      bf16_t* __restrict__ T1, int mg)
{
  int bxx, byy, bzz;
  swzA(mg, bxx, byy, bzz);
  const int z = bzz, hh = z >> 3, b = z & 7;
  GEMM256_PROLOG();
  const bf16_t* Ap0 = WqT + (long)hh * CC2 * CC2 + (long)bxx * 256 * CC2;
  const bf16_t* Bp0 = Gt + (long)b * KVD * CC2 + (long)byy * 256 * CC2;
  GEMM256_LOOP(Ap0, Bp0, CC2);
  bf16_t* Cb = T1 + (long)z * CC2 * KVD;
  const int rbase = bxx * 256, cbase = byy * 256;
  epi256(acc, wr, wc, lane, [&](int rr, int cc, float v) {
    Cb[(long)(rbase + rr) * KVD + cbase + cc] = (bf16_t)v;
  });
}

// scores: SC[z][c2][d] = sum_c T1[z][c2][c] WkT[hh][d][c] / sqrt(KV); + per-z sum/sumsq
__global__ __launch_bounds__(512, 2) void gemm_scores_256(const bf16_t* __restrict__ T1,
                                                          const bf16_t* __restrict__ WkT,
                                                          bf16_t* __restrict__ SC,
                                                          float* __restrict__ stats, int mg)
{
  int bxx, byy, bzz;
  swzA(mg, bxx, byy, bzz);
  const int z = bzz, hh = z >> 3;
  GEMM256_PROLOG();
  const bf16_t* Ap0 = T1 + (long)z * CC2 * KVD + (long)bxx * 256 * KVD;
  const bf16_t* Bp0 = WkT + (long)hh * KVD * KVD + (long)byy * 256 * KVD;
  GEMM256_LOOP(Ap0, Bp0, KVD);
  const float scale = 0.02362277854f;  // 1/sqrt(1792)
  bf16_t* Cb = SC + (long)z * CC2 * KVD;
  const int rbase = bxx * 256, cbase = byy * 256;
  float s = 0.f, q = 0.f;
  epi256(acc, wr, wc, lane, [&](int rr, int cc, float v) {
    v *= scale;
    Cb[(long)(rbase + rr) * KVD + cbase + cc] = (bf16_t)v;
    s += v; q += v * v;
  });
  for (int off = 32; off; off >>= 1) { s += __shfl_down(s, off, 64); q += __shfl_down(q, off, 64); }
  if (lane == 0) { sred[wave] = s; sred[8 + wave] = q; }
  __syncthreads();
  if (tid == 0) {
    float S = 0.f, Q = 0.f;
#pragma unroll
    for (int w = 0; w < 8; ++w) { S += sred[w]; Q += sred[8 + w]; }
    atomicAdd(&stats[2 * z], S);
    atomicAdd(&stats[2 * z + 1], Q);
  }
}

// Msum[z][c2][c] (+)= 0.25 * sum_d P[z][c2][d] WvB[hh][c][d]
__global__ __launch_bounds__(512, 2) void gemm_macc_256(const bf16_t* __restrict__ P,
                                                        const bf16_t* __restrict__ WvB,
                                                        bf16_t* __restrict__ M,
                                                        int first, int mg)
{
  int bxx, byy, bzz;
  swzA(mg, bxx, byy, bzz);
  const int z = bzz, hh = z >> 3;
  GEMM256_PROLOG();
  const bf16_t* Ap0 = P + (long)z * CC2 * KVD + (long)bxx * 256 * KVD;
  const bf16_t* Bp0 = WvB + (long)hh * KVD * KVD + (long)byy * 256 * KVD;
  GEMM256_LOOP(Ap0, Bp0, KVD);
  bf16_t* Cb = M + (long)z * CC2 * KVD;
  const int rbase = bxx * 256, cbase = byy * 256;
  epi256(acc, wr, wc, lane, [&](int rr, int cc, float v) {
    long idx = (long)(rbase + rr) * KVD + cbase + cc;
    float prev = first ? 0.f : (float)Cb[idx];
    Cb[idx] = (bf16_t)(prev + v * 0.25f);
  });
}

// ctx[b][n][c2] = sum_c E[b][n][c] Msum8[b][c2][c]   (Msum8 = head-folded)
__global__ __launch_bounds__(256) void gemm_ctx(const bf16_t* __restrict__ E,
                                                const bf16_t* __restrict__ Msum8,
                                                bf16_t* __restrict__ CTX)
{
  const int b = blockIdx.z;
  GEMM_PROLOG();
  const bf16_t* Ap = E + (long)b * NTOK * KVD + (long)blockIdx.x * 128 * KVD;
  const bf16_t* Bp = Msum8 + (long)b * CC2 * KVD + (long)blockIdx.y * 128 * KVD;
  GEMM_LOOP(Ap, Bp, KVD);
  bf16_t* Cb = CTX + (long)b * NTOK * CC2;
  const int rbase = blockIdx.x * 128, cbase = blockIdx.y * 128;
  epilogue_apply(acc, wr, wc, lane, [&](int rr, int cc, float v) {
    Cb[(long)(rbase + rr) * CC2 + cbase + cc] = (bf16_t)v;
  });
}

// o-proj + residual: CX2 = CTX@WOT^T + emb2 (fp32 out)
__global__ __launch_bounds__(256) void gemm_resid(const bf16_t* __restrict__ A,
                                                  const bf16_t* __restrict__ B,
                                                  const float* __restrict__ emb2,
                                                  float* __restrict__ CX2)
{
  GEMM_PROLOG();
  const bf16_t* Ap = A + (long)blockIdx.x * 128 * CC2;
  const bf16_t* Bp = B + (long)blockIdx.y * 128 * CC2;
  GEMM_LOOP(Ap, Bp, CC2);
  const int rbase = blockIdx.x * 128, cbase = blockIdx.y * 128;
  epilogue_apply(acc, wr, wc, lane, [&](int rr, int cc, float v) {
    long idx = (long)(rbase + rr) * CC2 + cbase + cc;
    CX2[idx] = v + emb2[idx];
  });
}

// fc1 + bias + exact gelu -> bf16 (256-core)
__global__ __launch_bounds__(512, 2) void gemm_gelu_256(const bf16_t* __restrict__ A,
                                                        const bf16_t* __restrict__ B,
                                                        const float* __restrict__ bias,
                                                        bf16_t* __restrict__ H)
{
  GEMM256_PROLOG();
  const bf16_t* Ap0 = A + (long)blockIdx.x * 256 * CC2;
  const bf16_t* Bp0 = B + (long)blockIdx.y * 256 * CC2;
  GEMM256_LOOP(Ap0, Bp0, CC2);
  const int rbase = blockIdx.x * 256, cbase = blockIdx.y * 256;
  epi256(acc, wr, wc, lane, [&](int rr, int cc, float v) {
    float x = v + bias[cbase + cc];
    float g = 0.5f * x * (1.0f + erff(x * 0.70710678118f));
    H[(long)(rbase + rr) * FFD + cbase + cc] = (bf16_t)g;
  });
}

// fc2 + bias + residual -> fp32 out
__global__ __launch_bounds__(256) void gemm_out(const bf16_t* __restrict__ A,
                                                const bf16_t* __restrict__ B,
                                                const float* __restrict__ bias,
                                                const float* __restrict__ CX2,
                                                float* __restrict__ OUT)
{
  GEMM_PROLOG();
  const bf16_t* Ap = A + (long)blockIdx.x * 128 * FFD;
  const bf16_t* Bp = B + (long)blockIdx.y * 128 * FFD;
  GEMM_LOOP(Ap, Bp, FFD);
  const int rbase = blockIdx.x * 128, cbase = blockIdx.y * 128;
  epilogue_apply(acc, wr, wc, lane, [&](int rr, int cc, float v) {
    long idx = (long)(rbase + rr) * CC2 + cbase + cc;
    OUT[idx] = v + bias[cbase + cc] + CX2[idx];
  });
}

// ---------------- host launcher -----------------------------------------------------------

extern "C" void kernel_launch(void* const* d_in, const int* in_sizes, int n_in,
                              void* d_out, int out_size, void* d_ws, size_t ws_size,
                              hipStream_t stream)
{
  const float* emb1   = (const float*)d_in[0];
  const float* emb2   = (const float*)d_in[1];
  const float* emb3   = (const float*)d_in[2];
  const float* Wq     = (const float*)d_in[3];
  const float* Wk     = (const float*)d_in[4];
  const float* Wv     = (const float*)d_in[5];
  const float* Wout   = (const float*)d_in[6];
  const float* ln1_g  = (const float*)d_in[7];
  const float* ln1_b  = (const float*)d_in[8];
  const float* lnall_g = (const float*)d_in[9];
  const float* lnall_b = (const float*)d_in[10];
  const float* lnffn_g = (const float*)d_in[11];
  const float* lnffn_b = (const float*)d_in[12];
  const float* fc1_w  = (const float*)d_in[13];
  const float* fc1_b  = (const float*)d_in[14];
  const float* fc2_w  = (const float*)d_in[15];
  const float* fc2_b  = (const float*)d_in[16];
  float* out = (float*)d_out;
  (void)in_sizes; (void)n_in; (void)out_size;

  // single-pass over all 4 heads needs ~304 MB workspace; else 2-pass (proven layout)
  const bool merged = ws_size >= (size_t)306 * 1000 * 1000;
  const int nheads = merged ? 4 : 2;   // heads transposed per attention pass
  const int nz = merged ? 32 : 16;     // z batches per GEMM launch
  const int nmslot = merged ? 32 : 16; // Msum slots

  char* ws = (char*)d_ws;
  size_t off = 0;
  auto alloc = [&](size_t bytes) {
    size_t r = off;
    off = (off + bytes + 255) & ~(size_t)255;
    return r;
  };

  size_t oEMBLN = alloc((size_t)ROWS * KVD * 2);
  size_t oCXLN  = alloc((size_t)ROWS * CC2 * 2);
  size_t oCX2   = alloc((size_t)ROWS * CC2 * 4);
  size_t oGt    = alloc((size_t)BSZ * KVD * CC2 * 2);
  size_t oMsum  = alloc((size_t)nmslot * CC2 * KVD * 2);
  size_t oWOT   = alloc((size_t)CC2 * CC2 * 2);
  size_t oF1T   = alloc((size_t)FFD * CC2 * 2);
  size_t oF2T   = alloc((size_t)CC2 * FFD * 2);
  size_t oSTATS = alloc(64 * 4);
  size_t oSCR   = alloc(0);
  size_t oCXLNT  = alloc((size_t)BSZ * CC2 * NTOK * 2);   // phase A (aliases scratch)
  size_t oEMBLNT = alloc((size_t)BSZ * KVD * NTOK * 2);

  bf16_t* EMBLN  = (bf16_t*)(ws + oEMBLN);
  bf16_t* CXLN   = (bf16_t*)(ws + oCXLN);
  float*  CX2    = (float*)(ws + oCX2);
  bf16_t* Gt     = (bf16_t*)(ws + oGt);
  bf16_t* Msum   = (bf16_t*)(ws + oMsum);
  bf16_t* WOT    = (bf16_t*)(ws + oWOT);
  bf16_t* F1T    = (bf16_t*)(ws + oF1T);
  bf16_t* F2T    = (bf16_t*)(ws + oF2T);
  float*  STATS  = (float*)(ws + oSTATS);
  bf16_t* CXLNT  = (bf16_t*)(ws + oCXLNT);
  bf16_t* EMBLNT = (bf16_t*)(ws + oEMBLNT);

  // phase B scratch: WqT | WkT | WvB | T1 | SC  (sized by nheads/nz)
  char* scr = ws + oSCR;
  auto rnd = [](size_t v) { return (v + 255) & ~(size_t)255; };
  bf16_t* WqT = (bf16_t*)(scr);
  bf16_t* WkT = (bf16_t*)(scr + rnd((size_t)nheads * CC2 * CC2 * 2));
  bf16_t* WvB = (bf16_t*)((char*)WkT + rnd((size_t)nheads * KVD * KVD * 2));
  bf16_t* T1  = (bf16_t*)((char*)WvB + rnd((size_t)nheads * KVD * KVD * 2));
  bf16_t* SC  = (bf16_t*)((char*)T1 + rnd((size_t)nz * CC2 * KVD * 2));
  // phase C aliases scratch: Msum8 (14.7) then CTX (8.4) then FFNH (33.5)
  bf16_t* Msum8 = (bf16_t*)(scr);
  bf16_t* CTX   = (bf16_t*)(scr + rnd((size_t)8 * CC2 * KVD * 2));
  bf16_t* FFNH  = (bf16_t*)((char*)CTX + rnd((size_t)ROWS * CC2 * 2));
  bf16_t* X2LN = CXLN;  // ffn-LN aliases cxln (dead after transposes)

  // stats zero + global weight transpose-converts
  zstats_k<<<1, 64, 0, stream>>>(STATS);
  tconv_k<<<dim3(16, 16), 256, 0, stream>>>(Wout, WOT, 512, 512);
  tconv_k<<<dim3(64, 16), 256, 0, stream>>>(fc1_w, F1T, 512, 2048);
  tconv_k<<<dim3(16, 64), 256, 0, stream>>>(fc2_w, F2T, 2048, 512);

  // fused layernorms -> bf16 activations
  ln_concat_k<<<8192, 256, 0, stream>>>(emb1, emb2, emb3, ln1_g, ln1_b,
                                        lnall_g, lnall_b, CXLN, EMBLN);

  // token-major transposes (once), then G^T[b][c][e] = sum_n E[n][c] CXLN[n][e]
  tconv_bf_k<<<dim3(16, 32, 8), 256, 0, stream>>>(CXLN, CXLNT, 1024, 512);
  tconv_bf_k<<<dim3(56, 32, 8), 256, 0, stream>>>(EMBLN, EMBLNT, 1024, 1792);
  gemm_ab<<<dim3(14, 4, 8), 256, 0, stream>>>(EMBLNT, (long)KVD * NTOK,
                                              CXLNT, (long)CC2 * NTOK,
                                              Gt, (long)KVD * CC2, NTOK, CC2);

  if (merged) {
    // single pass over all 4 heads: z = hh*8 + b, 32 batches per launch
    tconv_k<<<dim3(16, 16, 4), 256, 0, stream>>>(Wq, WqT, 512, 512);
    tconv_k<<<dim3(56, 56, 4), 256, 0, stream>>>(Wk, WkT, 1792, 1792);
    cast_k<<<12544, 256, 0, stream>>>(Wv, WvB, (long)4 * KVD * KVD);

    gemm_t1_256<<<dim3(2, 7, 32), 512, 0, stream>>>(WqT, Gt, T1, 1);
    gemm_scores_256<<<dim3(2, 7, 32), 512, 0, stream>>>(T1, WkT, SC, STATS, 1);
    softmax_k<<<16384, 256, 0, stream>>>(SC, STATS);
    gemm_macc_256<<<dim3(2, 7, 32), 512, 0, stream>>>(SC, WvB, Msum, 1, 1);
    msum_add_k<<<3584, 256, 0, stream>>>(Msum, Msum8, 4);
  } else {
    // two passes, two heads each (proven path)
    for (int g = 0; g < 2; ++g) {
      tconv_k<<<dim3(16, 16, 2), 256, 0, stream>>>(Wq + (long)g * 2 * CC2 * CC2, WqT, 512, 512);
      tconv_k<<<dim3(56, 56, 2), 256, 0, stream>>>(Wk + (long)g * 2 * KVD * KVD, WkT, 1792, 1792);
      cast_k<<<6272, 256, 0, stream>>>(Wv + (long)g * 2 * KVD * KVD, WvB, (long)2 * KVD * KVD);

      gemm_t1_256<<<dim3(2, 7, 16), 512, 0, stream>>>(WqT, Gt, T1, 0);
      gemm_scores_256<<<dim3(2, 7, 16), 512, 0, stream>>>(T1, WkT, SC, STATS + g * 32, 0);
      softmax_k<<<8192, 256, 0, stream>>>(SC, STATS + g * 32);
      gemm_macc_256<<<dim3(2, 7, 16), 512, 0, stream>>>(SC, WvB, Msum, g == 0 ? 1 : 0, 0);
    }
    msum_add_k<<<3584, 256, 0, stream>>>(Msum, Msum8, 2);
  }

  // ctx[b][n][c2] = E · Msum8[b]^T (single K=1792 pass)
  gemm_ctx<<<dim3(8, 4, 8), 256, 0, stream>>>(EMBLN, Msum8, CTX);

  // o-proj + residual
  gemm_resid<<<dim3(64, 4), 256, 0, stream>>>(CTX, WOT, emb2, CX2);

  // FFN
  ln2_k<<<8192, 256, 0, stream>>>(CX2, lnffn_g, lnffn_b, X2LN);
  gemm_gelu_256<<<dim3(32, 8), 512, 0, stream>>>(X2LN, F1T, fc1_b, FFNH);
  gemm_out<<<dim3(64, 4), 256, 0, stream>>>(FFNH, F2T, fc2_b, CX2, out);
}